// Round 3
// baseline (209.778 us; speedup 1.0000x reference)
//
#include <hip/hip_runtime.h>

// tp=4, T=4096, H=8192 (from setup_inputs).
constexpr int TP  = 4;
constexpr int TT  = 4096;
constexpr int HH  = 8192;
constexpr int BLK = 512;                 // 8 waves
constexpr int NJ  = HH / (BLK * 4);      // 4 float4 chunks per thread
constexpr int RPB = 4;                   // rows per (persistent-ish) block
constexpr int GRID = TT / RPB;           // 1024 blocks -> ~2 resident/CU, 2 queued

typedef float f32x4 __attribute__((ext_vector_type(4)));

// 16B-granular XOR swizzle: spreads 512B-strided lanes across LDS bank quads.
__device__ __forceinline__ unsigned swz(unsigned byte) {
    return byte ^ (((byte >> 9) & 7u) << 4);
}

// Raw barrier WITHOUT vmcnt drain: prefetched global loads stay in flight
// across phases (unlike __syncthreads, which drains vmcnt(0)).
__device__ __forceinline__ void barrier_lgkm() {
    asm volatile("s_waitcnt lgkmcnt(0)" ::: "memory");
    __builtin_amdgcn_s_barrier();
    asm volatile("" ::: "memory");
}

// Exact RNE to fp8-e4m3fn grid from a double that is exactly an f32 value
// already clipped to [-448, 448]. Power-of-two scalings are exact, so rint()
// performs the single correct rounding (matches ml_dtypes astype).
__device__ __forceinline__ double fp8_rne_d(double x) {
    long long b = (long long)__double_as_longlong(fabs(x));
    int ee = (int)(b >> 52);
    if (ee < 1017) ee = 1017;            // subnormal range: step 2^-9
    long long se = (long long)(ee - 3);  // step = 2^(e-3)
    double step = __longlong_as_double(se << 52);
    double inv  = __longlong_as_double((2046 - se) << 52);
    return rint(x * inv) * step;
}

__global__ __launch_bounds__(BLK, 4) void fused_ar_rms_fp8(
    const float* __restrict__ input,     // [TP, T, H]
    const float* __restrict__ residual,  // [T, H]
    const float* __restrict__ weight,    // [H]
    const float* __restrict__ scale,     // [1]
    float* __restrict__ quant,           // [T, H]
    float* __restrict__ resid_out)       // [T, H]
{
    __shared__ float lds[HH];            // 32 KB, swizzled staging of s
    __shared__ float bcast;

    const int tid = threadIdx.x;
    const size_t plane = (size_t)TT * HH;
    const size_t row0  = (size_t)blockIdx.x * RPB * HH;

    const f32x4* wv = (const f32x4*)weight;
    const float sc = scale[0];

    // Prefetch buffer for one row: 4 planes + residual, 4 chunks each.
    f32x4 cur[5 * NJ];                   // 80 VGPRs

    // Prologue: issue row 0 loads (nontemporal streaming).
    {
        const f32x4* i0 = (const f32x4*)(input + row0);
        const f32x4* rr = (const f32x4*)(residual + row0);
        #pragma unroll
        for (int j = 0; j < NJ; ++j) {
            const int idx = j * BLK + tid;
            cur[j * 5 + 0] = __builtin_nontemporal_load(&i0[idx]);
            cur[j * 5 + 1] = __builtin_nontemporal_load(&i0[plane / 4 + idx]);
            cur[j * 5 + 2] = __builtin_nontemporal_load(&i0[2 * (plane / 4) + idx]);
            cur[j * 5 + 3] = __builtin_nontemporal_load(&i0[3 * (plane / 4) + idx]);
            cur[j * 5 + 4] = __builtin_nontemporal_load(&rr[idx]);
        }
    }

    for (int r = 0; r < RPB; ++r) {
        const size_t row = row0 + (size_t)r * HH;
        f32x4* qo = (f32x4*)(quant + row);
        f32x4* ro = (f32x4*)(resid_out + row);

        float s[NJ * 4];

        // Phase 1: s = (((i0+i1)+i2)+i3)+res in f32 (numpy sequential order),
        // write residual_out, stage s in LDS (swizzled).
        #pragma unroll
        for (int j = 0; j < NJ; ++j) {
            const int idx = j * BLK + tid;
            f32x4 a = cur[j * 5 + 0], b = cur[j * 5 + 1];
            f32x4 c = cur[j * 5 + 2], d = cur[j * 5 + 3];
            f32x4 e = cur[j * 5 + 4];
            f32x4 sv;
            #pragma unroll
            for (int k = 0; k < 4; ++k) {
                float v = __fadd_rn(a[k], b[k]);
                v = __fadd_rn(v, c[k]);
                v = __fadd_rn(v, d[k]);
                v = __fadd_rn(v, e[k]);
                sv[k] = v;
                s[j * 4 + k] = v;
            }
            *(f32x4*)((char*)lds + swz(16u * (unsigned)idx)) = sv;
            __builtin_nontemporal_store(sv, &ro[idx]);
        }

        // Issue next row's loads now; they stream during P2/P3 (raw barriers
        // below do NOT drain vmcnt).
        if (r + 1 < RPB) {
            const size_t nrow = row + HH;
            const f32x4* i0 = (const f32x4*)(input + nrow);
            const f32x4* rr = (const f32x4*)(residual + nrow);
            #pragma unroll
            for (int j = 0; j < NJ; ++j) {
                const int idx = j * BLK + tid;
                cur[j * 5 + 0] = __builtin_nontemporal_load(&i0[idx]);
                cur[j * 5 + 1] = __builtin_nontemporal_load(&i0[plane / 4 + idx]);
                cur[j * 5 + 2] = __builtin_nontemporal_load(&i0[2 * (plane / 4) + idx]);
                cur[j * 5 + 3] = __builtin_nontemporal_load(&i0[3 * (plane / 4) + idx]);
                cur[j * 5 + 4] = __builtin_nontemporal_load(&rr[idx]);
            }
        }

        barrier_lgkm();

        // Phase 2 (wave 0): bit-exact numpy pairwise sum of squares, n=8192:
        // 64 leaves of 128 (8-acc unroll), perfect binary tree over leaves.
        if (tid < 64) {
            const unsigned base = 512u * (unsigned)tid;   // leaf byte offset
            float r8[8];
            f32x4 q0 = *(const f32x4*)((const char*)lds + swz(base));
            f32x4 q1 = *(const f32x4*)((const char*)lds + swz(base + 16));
            #pragma unroll
            for (int k = 0; k < 4; ++k) {
                r8[k]     = __fmul_rn(q0[k], q0[k]);
                r8[4 + k] = __fmul_rn(q1[k], q1[k]);
            }
            #pragma unroll
            for (int i = 1; i < 16; ++i) {
                const unsigned b2 = base + 32u * i;
                q0 = *(const f32x4*)((const char*)lds + swz(b2));
                q1 = *(const f32x4*)((const char*)lds + swz(b2 + 16));
                #pragma unroll
                for (int k = 0; k < 4; ++k) {
                    r8[k]     = __fadd_rn(r8[k],     __fmul_rn(q0[k], q0[k]));
                    r8[4 + k] = __fadd_rn(r8[4 + k], __fmul_rn(q1[k], q1[k]));
                }
            }
            float res = __fadd_rn(
                __fadd_rn(__fadd_rn(r8[0], r8[1]), __fadd_rn(r8[2], r8[3])),
                __fadd_rn(__fadd_rn(r8[4], r8[5]), __fadd_rn(r8[6], r8[7])));
            #pragma unroll
            for (int m = 1; m < 64; m <<= 1)
                res = __fadd_rn(res, __shfl_xor(res, m, 64));

            const float mean = __fmul_rn(res, 1.0f / 8192.0f);
            const float v    = __fadd_rn(mean, 1e-6f);
            const float rinv = __fdiv_rn(1.0f, __fsqrt_rn(v));
            if (tid == 0) bcast = rinv;
        }

        barrier_lgkm();

        const float rinv = bcast;

        // Phase 3: norm = ((s*rinv)*w)*sc, clip, exact fp8 RNE, store.
        #pragma unroll
        for (int j = 0; j < NJ; ++j) {
            const int idx = j * BLK + tid;
            f32x4 w4 = wv[idx];
            f32x4 qv;
            #pragma unroll
            for (int k = 0; k < 4; ++k) {
                float n = __fmul_rn(s[j * 4 + k], rinv);
                n = __fmul_rn(n, w4[k]);
                n = __fmul_rn(n, sc);
                n = fminf(fmaxf(n, -448.0f), 448.0f);
                qv[k] = (float)fp8_rne_d((double)n);
            }
            __builtin_nontemporal_store(qv, &qo[idx]);
        }

        // Next iteration overwrites lds[]; all waves passed barrier 2 after
        // completing their P2 reads, so no read-write race on lds[].
    }
}

extern "C" void kernel_launch(void* const* d_in, const int* in_sizes, int n_in,
                              void* d_out, int out_size, void* d_ws, size_t ws_size,
                              hipStream_t stream) {
    const float* input    = (const float*)d_in[0];
    const float* residual = (const float*)d_in[1];
    const float* weight   = (const float*)d_in[2];
    const float* scale    = (const float*)d_in[3];
    float* quant     = (float*)d_out;
    float* resid_out = (float*)d_out + (size_t)TT * HH;

    fused_ar_rms_fp8<<<GRID, BLK, 0, stream>>>(input, residual, weight, scale,
                                               quant, resid_out);
}

// Round 4
// 188.389 us; speedup vs baseline: 1.1135x; 1.1135x over previous
//
#include <hip/hip_runtime.h>

// tp=4, T=4096, H=8192 (from setup_inputs).
constexpr int TP  = 4;
constexpr int TT  = 4096;
constexpr int HH  = 8192;
constexpr int BLK = 512;                 // 8 waves
constexpr int NJ  = HH / (BLK * 4);      // 4 float4 chunks per thread

typedef float f32x4 __attribute__((ext_vector_type(4)));

// 16B-granular XOR swizzle: spreads 512B-strided accesses across bank quads.
// Phase-2 scalar reads (stride 32B within leaf, leaf stride 512B) land as a
// uniform 2-way conflict under this swizzle (2-way is free, m136).
__device__ __forceinline__ unsigned swz(unsigned byte) {
    return byte ^ (((byte >> 9) & 7u) << 4);
}

// Barrier WITHOUT vmcnt drain: in-flight global stores/loads keep streaming
// (__syncthreads would drain vmcnt(0)). LDS ordering is what we need here.
__device__ __forceinline__ void barrier_lgkm() {
    asm volatile("s_waitcnt lgkmcnt(0)" ::: "memory");
    __builtin_amdgcn_s_barrier();
    asm volatile("" ::: "memory");
}

// Exact RNE to fp8-e4m3fn grid from a double that is exactly an f32 value
// already clipped to [-448, 448]. Power-of-two scalings are exact, so rint()
// performs the single correct rounding (matches ml_dtypes astype).
__device__ __forceinline__ double fp8_rne_d(double x) {
    long long b = (long long)__double_as_longlong(fabs(x));
    int ee = (int)(b >> 52);
    if (ee < 1017) ee = 1017;            // subnormal range: step 2^-9
    long long se = (long long)(ee - 3);  // step = 2^(e-3)
    double step = __longlong_as_double(se << 52);
    double inv  = __longlong_as_double((2046 - se) << 52);
    return rint(x * inv) * step;
}

__global__ __launch_bounds__(BLK) void fused_ar_rms_fp8(
    const float* __restrict__ input,     // [TP, T, H]
    const float* __restrict__ residual,  // [T, H]
    const float* __restrict__ weight,    // [H]
    const float* __restrict__ scale,     // [1]
    float* __restrict__ quant,           // [T, H]
    float* __restrict__ resid_out)       // [T, H]
{
    __shared__ float lds[HH];            // 32 KB, swizzled staging of s
    __shared__ float sred[BLK / 64];     // per-wave partials

    const int t   = blockIdx.x;
    const int tid = threadIdx.x;
    const size_t row   = (size_t)t * HH;
    const size_t plane = (size_t)TT * HH;

    const f32x4* i0 = (const f32x4*)(input + row);
    const f32x4* i1 = (const f32x4*)(input + plane + row);
    const f32x4* i2 = (const f32x4*)(input + 2 * plane + row);
    const f32x4* i3 = (const f32x4*)(input + 3 * plane + row);
    const f32x4* rr = (const f32x4*)(residual + row);
    f32x4* qo = (f32x4*)(quant + row);
    f32x4* ro = (f32x4*)(resid_out + row);
    const f32x4* wv = (const f32x4*)weight;

    float s[NJ * 4];

    // Phase 1: s = (((i0+i1)+i2)+i3)+res in f32 (numpy sequential outer-axis
    // reduce order), write residual_out, stage s in LDS (swizzled).
    #pragma unroll
    for (int j = 0; j < NJ; ++j) {
        const int idx = j * BLK + tid;
        f32x4 a = i0[idx];
        f32x4 b = i1[idx];
        f32x4 c = i2[idx];
        f32x4 d = i3[idx];
        f32x4 r = rr[idx];
        f32x4 sv;
        #pragma unroll
        for (int k = 0; k < 4; ++k) {
            float v = __fadd_rn(a[k], b[k]);
            v = __fadd_rn(v, c[k]);
            v = __fadd_rn(v, d[k]);
            v = __fadd_rn(v, r[k]);
            sv[k] = v;
            s[j * 4 + k] = v;
        }
        *(f32x4*)((char*)lds + swz(16u * (unsigned)idx)) = sv;
        ro[idx] = sv;
    }
    barrier_lgkm();

    // Phase 2 (ALL 512 threads): bit-exact numpy pairwise sum of squares.
    // numpy(n=8192): 64 leaves of 128 elements, each leaf an 8-accumulator
    // unrolled chain of 16 steps, combined ((r0+r1)+(r2+r3))+((r4+r5)+(r6+r7));
    // leaves combined by a perfect binary tree.
    // thread -> leaf = tid>>3, acc = tid&7: one accumulator chain each.
    {
        const int leaf = tid >> 3;
        const int acc  = tid & 7;
        const unsigned base = (unsigned)(leaf * 512 + acc * 4);
        const char* lp = (const char*)lds;

        float x = *(const float*)(lp + swz(base));
        float r = __fmul_rn(x, x);
        #pragma unroll
        for (int i = 1; i < 16; ++i) {
            x = *(const float*)(lp + swz(base + 32u * i));
            r = __fadd_rn(r, __fmul_rn(x, x));
        }
        // Combine 8 accumulators (lanes differing in bits 0..2 = acc):
        // masks 1,2,4 reproduce ((r0+r1)+(r2+r3))+((r4+r5)+(r6+r7)).
        r = __fadd_rn(r, __shfl_xor(r, 1, 64));
        r = __fadd_rn(r, __shfl_xor(r, 2, 64));
        r = __fadd_rn(r, __shfl_xor(r, 4, 64));
        // Combine the wave's 8 leaves (tid bits 3..5): bottom subtree of the
        // 64-leaf perfect binary tree.
        r = __fadd_rn(r, __shfl_xor(r, 8, 64));
        r = __fadd_rn(r, __shfl_xor(r, 16, 64));
        r = __fadd_rn(r, __shfl_xor(r, 32, 64));
        if ((tid & 63) == 0) sred[tid >> 6] = r;
    }
    barrier_lgkm();

    // Top 3 tree levels over the 8 wave partials — every thread redundantly
    // (LDS broadcast reads, no extra barrier needed).
    const float rinv = [&]() {
        float p0 = sred[0], p1 = sred[1], p2 = sred[2], p3 = sred[3];
        float p4 = sred[4], p5 = sred[5], p6 = sred[6], p7 = sred[7];
        float res = __fadd_rn(
            __fadd_rn(__fadd_rn(p0, p1), __fadd_rn(p2, p3)),
            __fadd_rn(__fadd_rn(p4, p5), __fadd_rn(p6, p7)));
        const float mean = __fmul_rn(res, 1.0f / 8192.0f);  // exact pow2
        const float v    = __fadd_rn(mean, 1e-6f);
        return __fdiv_rn(1.0f, __fsqrt_rn(v));              // 1/np.sqrt
    }();
    const float sc = scale[0];

    // Phase 3: norm = ((s*rinv)*w)*sc, clip, exact fp8 RNE, store.
    #pragma unroll
    for (int j = 0; j < NJ; ++j) {
        const int idx = j * BLK + tid;
        f32x4 w4 = wv[idx];
        f32x4 qv;
        #pragma unroll
        for (int k = 0; k < 4; ++k) {
            float n = __fmul_rn(s[j * 4 + k], rinv);
            n = __fmul_rn(n, w4[k]);
            n = __fmul_rn(n, sc);
            n = fminf(fmaxf(n, -448.0f), 448.0f);
            qv[k] = (float)fp8_rne_d((double)n);
        }
        qo[idx] = qv;
    }
}

extern "C" void kernel_launch(void* const* d_in, const int* in_sizes, int n_in,
                              void* d_out, int out_size, void* d_ws, size_t ws_size,
                              hipStream_t stream) {
    const float* input    = (const float*)d_in[0];
    const float* residual = (const float*)d_in[1];
    const float* weight   = (const float*)d_in[2];
    const float* scale    = (const float*)d_in[3];
    float* quant     = (float*)d_out;
    float* resid_out = (float*)d_out + (size_t)TT * HH;

    fused_ar_rms_fp8<<<TT, BLK, 0, stream>>>(input, residual, weight, scale,
                                             quant, resid_out);
}

// Round 5
// 183.423 us; speedup vs baseline: 1.1437x; 1.0271x over previous
//
#include <hip/hip_runtime.h>

// tp=4, T=4096, H=8192 (from setup_inputs).
constexpr int TP  = 4;
constexpr int TT  = 4096;
constexpr int HH  = 8192;
constexpr int BLK = 1024;                // 16 waves
constexpr int NJ  = HH / (BLK * 4);      // 2 float4 chunks per thread

typedef float f32x4 __attribute__((ext_vector_type(4)));

// 16B-granular XOR swizzle: spreads 512B-strided accesses across bank quads.
// Phase-2 scalar reads (stride 32B within leaf, leaf stride 512B) become a
// uniform 2-way conflict under this swizzle (2-way is free, m136).
__device__ __forceinline__ unsigned swz(unsigned byte) {
    return byte ^ (((byte >> 9) & 7u) << 4);
}

// Exact RNE to fp8-e4m3fn grid from a double that is exactly an f32 value
// already clipped to [-448, 448]. Power-of-two scalings are exact, so rint()
// performs the single correct rounding (matches ml_dtypes astype).
__device__ __forceinline__ double fp8_rne_d(double x) {
    long long b = (long long)__double_as_longlong(fabs(x));
    int ee = (int)(b >> 52);
    if (ee < 1017) ee = 1017;            // subnormal range: step 2^-9
    long long se = (long long)(ee - 3);  // step = 2^(e-3)
    double step = __longlong_as_double(se << 52);
    double inv  = __longlong_as_double((2046 - se) << 52);
    return rint(x * inv) * step;
}

// 8 waves/EU -> VGPR cap 64 -> 2 blocks (32 waves) per CU.
__global__ __launch_bounds__(BLK, 8) void fused_ar_rms_fp8(
    const float* __restrict__ input,     // [TP, T, H]
    const float* __restrict__ residual,  // [T, H]
    const float* __restrict__ weight,    // [H]
    const float* __restrict__ scale,     // [1]
    float* __restrict__ quant,           // [T, H]
    float* __restrict__ resid_out)       // [T, H]
{
    __shared__ float lds[HH];            // 32 KB, swizzled staging of s
    __shared__ float sred[8];            // per-wave partials (waves 0..7)

    const int t   = blockIdx.x;
    const int tid = threadIdx.x;
    const size_t row   = (size_t)t * HH;
    const size_t plane = (size_t)TT * HH;

    const f32x4* i0 = (const f32x4*)(input + row);
    const f32x4* i1 = (const f32x4*)(input + plane + row);
    const f32x4* i2 = (const f32x4*)(input + 2 * plane + row);
    const f32x4* i3 = (const f32x4*)(input + 3 * plane + row);
    const f32x4* rr = (const f32x4*)(residual + row);
    f32x4* qo = (f32x4*)(quant + row);
    f32x4* ro = (f32x4*)(resid_out + row);
    const f32x4* wv = (const f32x4*)weight;

    float s[NJ * 4];                     // 8 registers

    // Phase 1: s = (((i0+i1)+i2)+i3)+res in f32 (numpy sequential outer-axis
    // reduce order), write residual_out, stage s in LDS (swizzled).
    #pragma unroll
    for (int j = 0; j < NJ; ++j) {
        const int idx = j * BLK + tid;
        f32x4 a = i0[idx];
        f32x4 b = i1[idx];
        f32x4 c = i2[idx];
        f32x4 d = i3[idx];
        f32x4 r = rr[idx];
        f32x4 sv;
        #pragma unroll
        for (int k = 0; k < 4; ++k) {
            float v = __fadd_rn(a[k], b[k]);
            v = __fadd_rn(v, c[k]);
            v = __fadd_rn(v, d[k]);
            v = __fadd_rn(v, r[k]);
            sv[k] = v;
            s[j * 4 + k] = v;
        }
        *(f32x4*)((char*)lds + swz(16u * (unsigned)idx)) = sv;
        ro[idx] = sv;
    }
    __syncthreads();

    // Phase 2 (waves 0..7 = 512 chains): bit-exact numpy pairwise sum of
    // squares. numpy(n=8192): 64 leaves of 128 elements, each an 8-accumulator
    // unrolled chain of 16 sequential steps, combined
    // ((r0+r1)+(r2+r3))+((r4+r5)+(r6+r7)); leaves combined by a perfect
    // binary tree. thread -> leaf = tid>>3, acc = tid&7.
    if (tid < 512) {
        const int leaf = tid >> 3;
        const int acc  = tid & 7;
        const unsigned base = (unsigned)(leaf * 512 + acc * 4);
        const char* lp = (const char*)lds;

        float x = *(const float*)(lp + swz(base));
        float r = __fmul_rn(x, x);
        #pragma unroll
        for (int i = 1; i < 16; ++i) {
            x = *(const float*)(lp + swz(base + 32u * i));
            r = __fadd_rn(r, __fmul_rn(x, x));
        }
        // masks 1,2,4: ((r0+r1)+(r2+r3))+((r4+r5)+(r6+r7))
        r = __fadd_rn(r, __shfl_xor(r, 1, 64));
        r = __fadd_rn(r, __shfl_xor(r, 2, 64));
        r = __fadd_rn(r, __shfl_xor(r, 4, 64));
        // wave's 8 leaves: bottom subtree of the 64-leaf tree
        r = __fadd_rn(r, __shfl_xor(r, 8, 64));
        r = __fadd_rn(r, __shfl_xor(r, 16, 64));
        r = __fadd_rn(r, __shfl_xor(r, 32, 64));
        if ((tid & 63) == 0) sred[tid >> 6] = r;
    }
    __syncthreads();

    // Top 3 tree levels over the 8 wave partials — every thread redundantly
    // (LDS broadcast reads).
    float p0 = sred[0], p1 = sred[1], p2 = sred[2], p3 = sred[3];
    float p4 = sred[4], p5 = sred[5], p6 = sred[6], p7 = sred[7];
    float res = __fadd_rn(
        __fadd_rn(__fadd_rn(p0, p1), __fadd_rn(p2, p3)),
        __fadd_rn(__fadd_rn(p4, p5), __fadd_rn(p6, p7)));
    const float mean = __fmul_rn(res, 1.0f / 8192.0f);   // exact pow2
    const float vv   = __fadd_rn(mean, 1e-6f);
    const float rinv = __fdiv_rn(1.0f, __fsqrt_rn(vv));  // 1/np.sqrt
    const float sc   = scale[0];

    // Phase 3: norm = ((s*rinv)*w)*sc, clip, exact fp8 RNE, store.
    #pragma unroll
    for (int j = 0; j < NJ; ++j) {
        const int idx = j * BLK + tid;
        f32x4 w4 = wv[idx];
        f32x4 qv;
        #pragma unroll
        for (int k = 0; k < 4; ++k) {
            float n = __fmul_rn(s[j * 4 + k], rinv);
            n = __fmul_rn(n, w4[k]);
            n = __fmul_rn(n, sc);
            n = fminf(fmaxf(n, -448.0f), 448.0f);
            qv[k] = (float)fp8_rne_d((double)n);
        }
        qo[idx] = qv;
    }
}

extern "C" void kernel_launch(void* const* d_in, const int* in_sizes, int n_in,
                              void* d_out, int out_size, void* d_ws, size_t ws_size,
                              hipStream_t stream) {
    const float* input    = (const float*)d_in[0];
    const float* residual = (const float*)d_in[1];
    const float* weight   = (const float*)d_in[2];
    const float* scale    = (const float*)d_in[3];
    float* quant     = (float*)d_out;
    float* resid_out = (float*)d_out + (size_t)TT * HH;

    fused_ar_rms_fp8<<<TT, BLK, 0, stream>>>(input, residual, weight, scale,
                                             quant, resid_out);
}

// Round 6
// 181.556 us; speedup vs baseline: 1.1554x; 1.0103x over previous
//
#include <hip/hip_runtime.h>

// tp=4, T=4096, H=8192 (from setup_inputs).
constexpr int TP  = 4;
constexpr int TT  = 4096;
constexpr int HH  = 8192;
constexpr int BLK = 256;                 // 4 waves; 32KB LDS -> 5 blocks/CU
constexpr int NJ  = HH / (BLK * 4);      // 8 float4 chunks per thread

typedef float f32x4 __attribute__((ext_vector_type(4)));

// 16B-granular XOR swizzle: spreads 512B-strided accesses across bank quads.
// Phase-2 scalar chain reads (stride 32B, leaf stride 512B) become a uniform
// 2-way conflict (free, m136); phase-1 b128 writes unchanged vs R1.
__device__ __forceinline__ unsigned swz(unsigned byte) {
    return byte ^ (((byte >> 9) & 7u) << 4);
}

// Exact RNE to fp8-e4m3fn grid, all-f32 (bit-identical to the f64 rounder
// that passed R2-R5). Input already clipped to [-448, 448].
// Normals (|n| >= 2^-6): RNE to 3 mantissa bits = drop 20 f32 mantissa bits
// via the integer round-half-to-even trick (carry into exponent is correct;
// 448 is closed under it). Subnormals: multiples of 2^-9 via exact pow-2
// scaling + v_rndne_f32.
__device__ __forceinline__ float fp8_rne_f(float n) {
    unsigned u = __float_as_uint(n);
    unsigned un = (u + 0x7FFFFu + ((u >> 20) & 1u)) & 0xFFF00000u;
    float qs = rintf(__fmul_rn(n, 512.0f)) * (1.0f / 512.0f);
    return ((u & 0x7FFFFFFFu) >= 0x3C800000u) ? __uint_as_float(un) : qs;
}

// 5 blocks/CU (LDS-capped): launch_bounds min-waves/EU = 5 -> VGPR cap ~102.
__global__ __launch_bounds__(BLK, 5) void fused_ar_rms_fp8(
    const float* __restrict__ input,     // [TP, T, H]
    const float* __restrict__ residual,  // [T, H]
    const float* __restrict__ weight,    // [H]
    const float* __restrict__ scale,     // [1]
    float* __restrict__ quant,           // [T, H]
    float* __restrict__ resid_out)       // [T, H]
{
    __shared__ float lds[HH];            // 32 KB, swizzled staging of s
    __shared__ float sred[4];            // per-wave partials

    const int t   = blockIdx.x;
    const int tid = threadIdx.x;
    const size_t row   = (size_t)t * HH;
    const size_t plane = (size_t)TT * HH;

    const f32x4* i0 = (const f32x4*)(input + row);
    const f32x4* i1 = (const f32x4*)(input + plane + row);
    const f32x4* i2 = (const f32x4*)(input + 2 * plane + row);
    const f32x4* i3 = (const f32x4*)(input + 3 * plane + row);
    const f32x4* rr = (const f32x4*)(residual + row);
    f32x4* qo = (f32x4*)(quant + row);
    f32x4* ro = (f32x4*)(resid_out + row);
    const f32x4* wv = (const f32x4*)weight;

    float s[NJ * 4];                     // 32 registers

    // Phase 1: s = (((i0+i1)+i2)+i3)+res in f32 (numpy sequential outer-axis
    // reduce order), write residual_out, stage s in LDS (swizzled).
    #pragma unroll
    for (int j = 0; j < NJ; ++j) {
        const int idx = j * BLK + tid;
        f32x4 a = i0[idx];
        f32x4 b = i1[idx];
        f32x4 c = i2[idx];
        f32x4 d = i3[idx];
        f32x4 r = rr[idx];
        f32x4 sv;
        #pragma unroll
        for (int k = 0; k < 4; ++k) {
            float v = __fadd_rn(a[k], b[k]);
            v = __fadd_rn(v, c[k]);
            v = __fadd_rn(v, d[k]);
            v = __fadd_rn(v, r[k]);
            sv[k] = v;
            s[j * 4 + k] = v;
        }
        *(f32x4*)((char*)lds + swz(16u * (unsigned)idx)) = sv;
        ro[idx] = sv;
    }
    __syncthreads();

    // Phase 2 (all 256 threads, 2 chains each): bit-exact numpy pairwise sum
    // of squares. numpy(n=8192): 64 leaves of 128, each an 8-accumulator
    // chain of 16 sequential steps, combined
    // ((r0+r1)+(r2+r3))+((r4+r5)+(r6+r7)); leaves by perfect binary tree.
    // thread -> leaf = wave*16 + (lane>>2); accs = lane&3 and (lane&3)+4.
    {
        const int wave = tid >> 6;
        const int lane = tid & 63;
        const int leaf = wave * 16 + (lane >> 2);
        const unsigned baseL = (unsigned)(leaf * 512 + (lane & 3) * 4);
        const char* lp = (const char*)lds;

        float xl = *(const float*)(lp + swz(baseL));
        float xh = *(const float*)(lp + swz(baseL + 16));
        float rL = __fmul_rn(xl, xl);
        float rH = __fmul_rn(xh, xh);
        #pragma unroll
        for (int i = 1; i < 16; ++i) {
            xl = *(const float*)(lp + swz(baseL + 32u * i));
            xh = *(const float*)(lp + swz(baseL + 32u * i + 16));
            rL = __fadd_rn(rL, __fmul_rn(xl, xl));
            rH = __fadd_rn(rH, __fmul_rn(xh, xh));
        }
        // (r0+r1)+(r2+r3) on the low accs, (r4+r5)+(r6+r7) on the high accs:
        rL = __fadd_rn(rL, __shfl_xor(rL, 1, 64));
        rL = __fadd_rn(rL, __shfl_xor(rL, 2, 64));
        rH = __fadd_rn(rH, __shfl_xor(rH, 1, 64));
        rH = __fadd_rn(rH, __shfl_xor(rH, 2, 64));
        float r = __fadd_rn(rL, rH);      // leaf total, exact numpy combine
        // Perfect binary tree over the wave's 16 leaves (lane bits 2..5):
        r = __fadd_rn(r, __shfl_xor(r, 4, 64));
        r = __fadd_rn(r, __shfl_xor(r, 8, 64));
        r = __fadd_rn(r, __shfl_xor(r, 16, 64));
        r = __fadd_rn(r, __shfl_xor(r, 32, 64));
        if (lane == 0) sred[wave] = r;
    }
    __syncthreads();

    // Top 2 tree levels over the 4 wave partials — every thread redundantly.
    const float res = __fadd_rn(__fadd_rn(sred[0], sred[1]),
                                __fadd_rn(sred[2], sred[3]));
    const float mean = __fmul_rn(res, 1.0f / 8192.0f);   // exact pow2
    const float vv   = __fadd_rn(mean, 1e-6f);
    const float rinv = __fdiv_rn(1.0f, __fsqrt_rn(vv));  // 1/np.sqrt
    const float sc   = scale[0];

    // Phase 3: norm = ((s*rinv)*w)*sc, clip, exact fp8 RNE, store.
    #pragma unroll
    for (int j = 0; j < NJ; ++j) {
        const int idx = j * BLK + tid;
        f32x4 w4 = wv[idx];
        f32x4 qv;
        #pragma unroll
        for (int k = 0; k < 4; ++k) {
            float n = __fmul_rn(s[j * 4 + k], rinv);
            n = __fmul_rn(n, w4[k]);
            n = __fmul_rn(n, sc);
            n = fminf(fmaxf(n, -448.0f), 448.0f);
            qv[k] = fp8_rne_f(n);
        }
        qo[idx] = qv;
    }
}

extern "C" void kernel_launch(void* const* d_in, const int* in_sizes, int n_in,
                              void* d_out, int out_size, void* d_ws, size_t ws_size,
                              hipStream_t stream) {
    const float* input    = (const float*)d_in[0];
    const float* residual = (const float*)d_in[1];
    const float* weight   = (const float*)d_in[2];
    const float* scale    = (const float*)d_in[3];
    float* quant     = (float*)d_out;
    float* resid_out = (float*)d_out + (size_t)TT * HH;

    fused_ar_rms_fp8<<<TT, BLK, 0, stream>>>(input, residual, weight, scale,
                                             quant, resid_out);
}

// Round 7
// 161.694 us; speedup vs baseline: 1.2974x; 1.1228x over previous
//
#include <hip/hip_runtime.h>

// tp=4, T=4096, H=8192 (from setup_inputs).
constexpr int TP  = 4;
constexpr int TT  = 4096;
constexpr int HH  = 8192;
constexpr int BLK = 256;                 // 4 waves; 32KB LDS -> 5 blocks/CU
constexpr int NJ  = HH / (BLK * 4);      // 8 float4 chunks per thread

typedef float f32x4 __attribute__((ext_vector_type(4)));

// 16B-granular XOR swizzle: spreads 512B-strided accesses across bank quads.
// Phase-2 scalar chain reads (stride 32B, leaf stride 512B) become a uniform
// 2-way conflict (free, m136).
__device__ __forceinline__ unsigned swz(unsigned byte) {
    return byte ^ (((byte >> 9) & 7u) << 4);
}

// Exact RNE to fp8-e4m3fn grid, all-f32 (passed R6 at absmax 0.125).
// Input already clipped to [-448, 448]. Normals (|n| >= 2^-6): integer
// round-half-to-even dropping 20 mantissa bits (carry into exponent correct;
// 448 closed under it). Subnormals: exact pow-2 scaling + v_rndne_f32.
__device__ __forceinline__ float fp8_rne_f(float n) {
    unsigned u = __float_as_uint(n);
    unsigned un = (u + 0x7FFFFu + ((u >> 20) & 1u)) & 0xFFF00000u;
    float qs = rintf(__fmul_rn(n, 512.0f)) * (1.0f / 512.0f);
    return ((u & 0x7FFFFFFFu) >= 0x3C800000u) ? __uint_as_float(un) : qs;
}

__global__ __launch_bounds__(BLK, 5) void fused_ar_rms_fp8(
    const float* __restrict__ input,     // [TP, T, H]
    const float* __restrict__ residual,  // [T, H]
    const float* __restrict__ weight,    // [H]
    const float* __restrict__ scale,     // [1]
    float* __restrict__ quant,           // [T, H]
    float* __restrict__ resid_out)       // [T, H]
{
    __shared__ float lds[HH];            // 32 KB, swizzled staging of s
    __shared__ float sred[4];            // per-wave partials

    const int t   = blockIdx.x;
    const int tid = threadIdx.x;
    const size_t row   = (size_t)t * HH;
    const size_t plane = (size_t)TT * HH;

    const f32x4* i0 = (const f32x4*)(input + row);
    const f32x4* i1 = (const f32x4*)(input + plane + row);
    const f32x4* i2 = (const f32x4*)(input + 2 * plane + row);
    const f32x4* i3 = (const f32x4*)(input + 3 * plane + row);
    const f32x4* rr = (const f32x4*)(residual + row);
    f32x4* qo = (f32x4*)(quant + row);
    f32x4* ro = (f32x4*)(resid_out + row);
    const f32x4* wv = (const f32x4*)weight;

    // Phase 1 — stream-burst ordering: consume each of the 5 read streams as
    // one 8-chunk contiguous burst (8KB/wave) instead of round-robin 1KB
    // switches. Element-wise add order is unchanged: ((((i0+i1)+i2)+i3)+r),
    // each step __fadd_rn — bit-identical to R6.
    f32x4 A[NJ];                          // 32 registers (the running sum)

    #pragma unroll
    for (int j = 0; j < NJ; ++j)
        A[j] = __builtin_nontemporal_load(&i0[j * BLK + tid]);

    #pragma unroll
    for (int j = 0; j < NJ; ++j) {
        f32x4 b = __builtin_nontemporal_load(&i1[j * BLK + tid]);
        #pragma unroll
        for (int k = 0; k < 4; ++k) A[j][k] = __fadd_rn(A[j][k], b[k]);
    }
    #pragma unroll
    for (int j = 0; j < NJ; ++j) {
        f32x4 b = __builtin_nontemporal_load(&i2[j * BLK + tid]);
        #pragma unroll
        for (int k = 0; k < 4; ++k) A[j][k] = __fadd_rn(A[j][k], b[k]);
    }
    #pragma unroll
    for (int j = 0; j < NJ; ++j) {
        f32x4 b = __builtin_nontemporal_load(&i3[j * BLK + tid]);
        #pragma unroll
        for (int k = 0; k < 4; ++k) A[j][k] = __fadd_rn(A[j][k], b[k]);
    }
    #pragma unroll
    for (int j = 0; j < NJ; ++j) {
        const int idx = j * BLK + tid;
        f32x4 b = __builtin_nontemporal_load(&rr[idx]);
        f32x4 sv;
        #pragma unroll
        for (int k = 0; k < 4; ++k) sv[k] = __fadd_rn(A[j][k], b[k]);
        A[j] = sv;
        *(f32x4*)((char*)lds + swz(16u * (unsigned)idx)) = sv;
        __builtin_nontemporal_store(sv, &ro[idx]);
    }
    __syncthreads();

    // Phase 2 (all 256 threads, 2 chains each): bit-exact numpy pairwise sum
    // of squares (identical to R6). 64 leaves of 128, 8-acc chains of 16
    // steps, ((r0+r1)+(r2+r3))+((r4+r5)+(r6+r7)), perfect tree over leaves.
    {
        const int wave = tid >> 6;
        const int lane = tid & 63;
        const int leaf = wave * 16 + (lane >> 2);
        const unsigned baseL = (unsigned)(leaf * 512 + (lane & 3) * 4);
        const char* lp = (const char*)lds;

        float xl = *(const float*)(lp + swz(baseL));
        float xh = *(const float*)(lp + swz(baseL + 16));
        float rL = __fmul_rn(xl, xl);
        float rH = __fmul_rn(xh, xh);
        #pragma unroll
        for (int i = 1; i < 16; ++i) {
            xl = *(const float*)(lp + swz(baseL + 32u * i));
            xh = *(const float*)(lp + swz(baseL + 32u * i + 16));
            rL = __fadd_rn(rL, __fmul_rn(xl, xl));
            rH = __fadd_rn(rH, __fmul_rn(xh, xh));
        }
        rL = __fadd_rn(rL, __shfl_xor(rL, 1, 64));
        rL = __fadd_rn(rL, __shfl_xor(rL, 2, 64));
        rH = __fadd_rn(rH, __shfl_xor(rH, 1, 64));
        rH = __fadd_rn(rH, __shfl_xor(rH, 2, 64));
        float r = __fadd_rn(rL, rH);      // leaf total, exact numpy combine
        r = __fadd_rn(r, __shfl_xor(r, 4, 64));
        r = __fadd_rn(r, __shfl_xor(r, 8, 64));
        r = __fadd_rn(r, __shfl_xor(r, 16, 64));
        r = __fadd_rn(r, __shfl_xor(r, 32, 64));
        if (lane == 0) sred[wave] = r;
    }
    __syncthreads();

    // Top 2 tree levels over the 4 wave partials — every thread redundantly.
    const float res = __fadd_rn(__fadd_rn(sred[0], sred[1]),
                                __fadd_rn(sred[2], sred[3]));
    const float mean = __fmul_rn(res, 1.0f / 8192.0f);   // exact pow2
    const float vv   = __fadd_rn(mean, 1e-6f);
    const float rinv = __fdiv_rn(1.0f, __fsqrt_rn(vv));  // 1/np.sqrt
    const float sc   = scale[0];

    // Phase 3: norm = ((s*rinv)*w)*sc, clip, exact fp8 RNE, store.
    #pragma unroll
    for (int j = 0; j < NJ; ++j) {
        const int idx = j * BLK + tid;
        f32x4 w4 = wv[idx];
        f32x4 qv;
        #pragma unroll
        for (int k = 0; k < 4; ++k) {
            float n = __fmul_rn(A[j][k], rinv);
            n = __fmul_rn(n, w4[k]);
            n = __fmul_rn(n, sc);
            n = fminf(fmaxf(n, -448.0f), 448.0f);
            qv[k] = fp8_rne_f(n);
        }
        __builtin_nontemporal_store(qv, &qo[idx]);
    }
}

extern "C" void kernel_launch(void* const* d_in, const int* in_sizes, int n_in,
                              void* d_out, int out_size, void* d_ws, size_t ws_size,
                              hipStream_t stream) {
    const float* input    = (const float*)d_in[0];
    const float* residual = (const float*)d_in[1];
    const float* weight   = (const float*)d_in[2];
    const float* scale    = (const float*)d_in[3];
    float* quant     = (float*)d_out;
    float* resid_out = (float*)d_out + (size_t)TT * HH;

    fused_ar_rms_fp8<<<TT, BLK, 0, stream>>>(input, residual, weight, scale,
                                             quant, resid_out);
}